// Round 2
// baseline (191.475 us; speedup 1.0000x reference)
//
#include <hip/hip_runtime.h>
#include <hip/hip_bf16.h>

typedef __attribute__((ext_vector_type(8))) short bf16x8;
typedef __attribute__((ext_vector_type(4))) float f32x4;

#define MFMA16(a, b, c) __builtin_amdgcn_mfma_f32_16x16x32_bf16(a, b, c, 0, 0, 0)

static constexpr int S = 2048;
static constexpr int D = 128;
static constexpr int QT = 64;   // Q rows per block (16 per wave)
static constexpr int KT = 64;   // KV rows per tile

// fp32 -> bf16 round-to-nearest-even
__device__ inline unsigned short f2b(float f) {
    union { float f; unsigned int u; } v; v.f = f;
    unsigned int u = v.u;
    return (unsigned short)((u + 0x7FFFu + ((u >> 16) & 1u)) >> 16);
}
__device__ inline float b2f(unsigned short h) {
    union { unsigned int u; float f; } v; v.u = ((unsigned int)h) << 16;
    return v.f;
}
__device__ inline unsigned int pack2(float a, float b) {
    return (unsigned int)f2b(a) | ((unsigned int)f2b(b) << 16);
}

__global__ __launch_bounds__(256) void bimodal_attn_kernel(
    const float* __restrict__ X, const float* __restrict__ Y,
    float* __restrict__ Out)
{
    const int bid = blockIdx.x;
    const int qt = bid & 31;          // 32 q-tiles
    const int p  = (bid >> 5) & 1;    // pass
    const int b  = bid >> 6;          // batch

    const float* Q  = p ? Y : X;
    const float* KV = p ? X : Y;
    const int ocol = p * D;

    __shared__ unsigned short Khi[KT * D];      // [64][128] bf16 hi, XOR-swizzled rows (256B)
    __shared__ unsigned short Klo[KT * D];      // [64][128] bf16 lo (residual)
    __shared__ unsigned short Vt[D * KT];       // [128][64] bf16 transposed, XOR-swizzled rows (128B)
    __shared__ unsigned short Psh[4][16 * 72];  // per-wave P tile, padded pitch 72

    const int tid = threadIdx.x;
    const int wv = tid >> 6;
    const int lane = tid & 63;
    const int c = lane & 15;          // frag row/col index
    const int g = lane >> 4;          // 16-lane group

    const int i0 = qt * QT + wv * 16; // this wave's first Q row

    // ---- load Q fragments hi/lo (A-layout: row=c, k = 32*kc + 8*g + i) ----
    const float* qbase = Q + ((size_t)(b * S + i0 + c)) * D;
    bf16x8 qhi[4], qlo[4];
#pragma unroll
    for (int kc = 0; kc < 4; ++kc) {
        const float* qp = qbase + kc * 32 + g * 8;
        float4 f0 = *(const float4*)qp;
        float4 f1 = *(const float4*)(qp + 4);
        float fv[8] = {f0.x, f0.y, f0.z, f0.w, f1.x, f1.y, f1.z, f1.w};
        bf16x8 th, tl;
#pragma unroll
        for (int i = 0; i < 8; ++i) {
            unsigned short h = f2b(fv[i]);
            th[i] = (short)h;
            tl[i] = (short)f2b(fv[i] - b2f(h));
        }
        qhi[kc] = th; qlo[kc] = tl;
    }

    f32x4 o[8];
#pragma unroll
    for (int nb = 0; nb < 8; ++nb) { o[nb][0] = 0.f; o[nb][1] = 0.f; o[nb][2] = 0.f; o[nb][3] = 0.f; }
    float m[4], l[4];
#pragma unroll
    for (int r = 0; r < 4; ++r) { m[r] = -1e30f; l[r] = 0.f; }

    const float* kvb = KV + (size_t)b * S * D;
    unsigned short* pbuf = Psh[wv];

    for (int j0 = 0; j0 < S; j0 += KT) {
        // ---- stage K tile hi/lo: [64][128] fp32 -> bf16 LDS, swizzled ----
#pragma unroll
        for (int t = 0; t < 4; ++t) {
            int task = tid + t * 256;          // 1024 chunks of 8 elems
            int jr = task >> 4, sl = task & 15;
            const float* src = kvb + (size_t)(j0 + jr) * D + sl * 8;
            float4 f0 = *(const float4*)src;
            float4 f1 = *(const float4*)(src + 4);
            float fv[8] = {f0.x, f0.y, f0.z, f0.w, f1.x, f1.y, f1.z, f1.w};
            unsigned short hv[8];
            float lv[8];
#pragma unroll
            for (int i = 0; i < 8; ++i) {
                hv[i] = f2b(fv[i]);
                lv[i] = fv[i] - b2f(hv[i]);
            }
            uint4 wh, wl;
            wh.x = (unsigned int)hv[0] | ((unsigned int)hv[1] << 16);
            wh.y = (unsigned int)hv[2] | ((unsigned int)hv[3] << 16);
            wh.z = (unsigned int)hv[4] | ((unsigned int)hv[5] << 16);
            wh.w = (unsigned int)hv[6] | ((unsigned int)hv[7] << 16);
            wl.x = pack2(lv[0], lv[1]); wl.y = pack2(lv[2], lv[3]);
            wl.z = pack2(lv[4], lv[5]); wl.w = pack2(lv[6], lv[7]);
            int byte = jr * 256 + sl * 16;
            byte ^= (jr & 7) << 4;
            *(uint4*)((char*)Khi + byte) = wh;
            *(uint4*)((char*)Klo + byte) = wl;
        }
        // ---- stage V transposed: Vt[d][j], swizzled ----
#pragma unroll
        for (int t = 0; t < 2; ++t) {
            int task = tid + t * 256;          // 512 tasks: 32 j-pairs x 16 d-chunks
            int jp = task & 31, dc = task >> 5;
            const float* s0 = kvb + (size_t)(j0 + 2 * jp) * D + dc * 8;
            const float* s1 = s0 + D;
            float4 a0 = *(const float4*)s0, a1 = *(const float4*)(s0 + 4);
            float4 b0 = *(const float4*)s1, b1 = *(const float4*)(s1 + 4);
            float av[8] = {a0.x, a0.y, a0.z, a0.w, a1.x, a1.y, a1.z, a1.w};
            float bv[8] = {b0.x, b0.y, b0.z, b0.w, b1.x, b1.y, b1.z, b1.w};
#pragma unroll
            for (int i = 0; i < 8; ++i) {
                int d = dc * 8 + i;
                int byte = d * 128 + jp * 4;
                byte ^= (d & 7) << 4;
                *(unsigned int*)((char*)Vt + byte) = pack2(av[i], bv[i]);
            }
        }
        __syncthreads();

        // ---- S = Q K^T tile: 16 x 64, split-bf16 (hi*hi + hi*lo + lo*hi) ----
        f32x4 sF[4];
#pragma unroll
        for (int nb = 0; nb < 4; ++nb) {
            f32x4 acc; acc[0] = 0.f; acc[1] = 0.f; acc[2] = 0.f; acc[3] = 0.f;
#pragma unroll
            for (int kc = 0; kc < 4; ++kc) {
                int row = nb * 16 + c;
                int byte = row * 256 + (kc * 32 + g * 8) * 2;
                byte ^= (row & 7) << 4;
                bf16x8 kh = *(const bf16x8*)((char*)Khi + byte);
                bf16x8 kl = *(const bf16x8*)((char*)Klo + byte);
                acc = MFMA16(qhi[kc], kh, acc);
                acc = MFMA16(qhi[kc], kl, acc);
                acc = MFMA16(qlo[kc], kh, acc);
            }
            sF[nb] = acc;
        }

        // ---- online softmax (rows = 4*g + r, cols spread over 16-lane group) ----
#pragma unroll
        for (int r = 0; r < 4; ++r) {
            float v = fmaxf(fmaxf(sF[0][r], sF[1][r]), fmaxf(sF[2][r], sF[3][r]));
            v = fmaxf(v, __shfl_xor(v, 1));
            v = fmaxf(v, __shfl_xor(v, 2));
            v = fmaxf(v, __shfl_xor(v, 4));
            v = fmaxf(v, __shfl_xor(v, 8));
            float mn = fmaxf(m[r], v);
            float alpha = __expf(m[r] - mn);
            m[r] = mn;
            float rs = 0.f;
#pragma unroll
            for (int nb = 0; nb < 4; ++nb) {
                float pv = __expf(sF[nb][r] - mn);
                sF[nb][r] = pv;
                rs += pv;
            }
            rs += __shfl_xor(rs, 1);
            rs += __shfl_xor(rs, 2);
            rs += __shfl_xor(rs, 4);
            rs += __shfl_xor(rs, 8);
            l[r] = l[r] * alpha + rs;
#pragma unroll
            for (int nb = 0; nb < 8; ++nb) o[nb][r] *= alpha;
        }

        // ---- P (C-layout f32) -> LDS -> A-layout bf16 frags ----
#pragma unroll
        for (int nb = 0; nb < 4; ++nb)
#pragma unroll
            for (int r = 0; r < 4; ++r)
                pbuf[(g * 4 + r) * 72 + nb * 16 + c] = f2b(sF[nb][r]);

        bf16x8 pa[2];
#pragma unroll
        for (int kc = 0; kc < 2; ++kc)
            pa[kc] = *(const bf16x8*)(pbuf + c * 72 + kc * 32 + g * 8);

        // ---- O += P V ----
#pragma unroll
        for (int nb = 0; nb < 8; ++nb) {
#pragma unroll
            for (int kc = 0; kc < 2; ++kc) {
                int d = nb * 16 + c;
                int byte = d * 128 + (kc * 32 + g * 8) * 2;
                byte ^= (d & 7) << 4;
                bf16x8 vf = *(const bf16x8*)((char*)Vt + byte);
                o[nb] = MFMA16(pa[kc], vf, o[nb]);
            }
        }
        __syncthreads();
    }

    // ---- epilogue: normalize, gate by Q, store ----
    float* outb = Out + ((size_t)(b * S + i0)) * (2 * D) + ocol;
    const float* qg = Q + (size_t)(b * S + i0) * D;
#pragma unroll
    for (int r = 0; r < 4; ++r) {
        int row = g * 4 + r;
        float inv = 1.f / l[r];
#pragma unroll
        for (int nb = 0; nb < 8; ++nb) {
            int col = nb * 16 + c;
            float qv = qg[(size_t)row * D + col];
            outb[(size_t)row * (2 * D) + col] = o[nb][r] * inv * qv;
        }
    }
}

extern "C" void kernel_launch(void* const* d_in, const int* in_sizes, int n_in,
                              void* d_out, int out_size, void* d_ws, size_t ws_size,
                              hipStream_t stream) {
    const float* x = (const float*)d_in[0];
    const float* y = (const float*)d_in[1];
    float* out = (float*)d_out;
    const int B = 8;
    dim3 grid(B * 2 * (S / QT));
    dim3 block(256);
    hipLaunchKernelGGL(bimodal_attn_kernel, grid, block, 0, stream, x, y, out);
}

// Round 4
// 76.986 us; speedup vs baseline: 2.4871x; 2.4871x over previous
//
#include <hip/hip_runtime.h>
#include <hip/hip_bf16.h>

typedef __attribute__((ext_vector_type(8))) short bf16x8;
typedef __attribute__((ext_vector_type(8))) _Float16 f16x8;
typedef __attribute__((ext_vector_type(4))) float f32x4;
typedef __attribute__((ext_vector_type(4))) unsigned int u32x4;

#define MFMA16B(a, b, c) __builtin_amdgcn_mfma_f32_16x16x32_bf16(a, b, c, 0, 0, 0)
#define MFMA16F(a, b, c) __builtin_amdgcn_mfma_f32_16x16x32_f16(a, b, c, 0, 0, 0)

static constexpr int S = 2048;
static constexpr int D = 128;
static constexpr int QT = 64;   // Q rows per block (16 per wave)
static constexpr int KT = 64;   // KV rows per tile

// ---------------- helpers ----------------
__device__ inline unsigned short f2b(float f) {      // fp32->bf16 RNE
    union { float f; unsigned int u; } v; v.f = f;
    unsigned int u = v.u;
    return (unsigned short)((u + 0x7FFFu + ((u >> 16) & 1u)) >> 16);
}
__device__ inline float b2f(unsigned short h) {
    union { unsigned int u; float f; } v; v.u = ((unsigned int)h) << 16;
    return v.f;
}
__device__ inline unsigned int pack2(float a, float b) {
    return (unsigned int)f2b(a) | ((unsigned int)f2b(b) << 16);
}
__device__ inline unsigned int pkh(float a, float b) {  // fp32->fp16 RNE pair
    union { _Float16 h; unsigned short u; } ua, ub;
    ua.h = (_Float16)a; ub.h = (_Float16)b;
    return (unsigned int)ua.u | ((unsigned int)ub.u << 16);
}

// ---------------- prep: fp32 -> fp16, pre-swizzled K and V^T layouts ----------------
// ws layout (ushort units): [mat(0=X,1=Y)][role(0=Kf,1=VT)] each 8*2048*128 elems.
// Kf tile (b,t): 64 rows x 128 d, byte = jr*256 + 2d, XOR ((jr&7)<<4)
// VT tile (b,t): 128 rows d x 64 j, byte = d*128 + 2j, XOR ((d&7)<<4)
__global__ __launch_bounds__(256) void bimodal_prep(
    const float* __restrict__ X, const float* __restrict__ Y,
    unsigned short* __restrict__ WS)
{
    const int bid = blockIdx.x;          // [mat(2)][b(8)][t(32)]
    const int t = bid & 31;
    const int b = (bid >> 5) & 7;
    const int mat = bid >> 8;
    const float* src = mat ? Y : X;
    char* kf = (char*)(WS + (size_t)(mat * 2 + 0) * (8ull * S * D)) + (size_t)(b * 32 + t) * 16384;
    char* vt = (char*)(WS + (size_t)(mat * 2 + 1) * (8ull * S * D)) + (size_t)(b * 32 + t) * 16384;

    __shared__ float ftile[64][129];
    const int tid = threadIdx.x;
    const float* tsrc = src + ((size_t)(b * S + t * 64)) * D;
#pragma unroll
    for (int it = 0; it < 8; ++it) {
        int idx = tid + it * 256;        // 2048 float4 chunks
        int row = idx >> 5, ch = idx & 31;
        float4 v = *(const float4*)(tsrc + (size_t)row * D + ch * 4);
        ftile[row][ch * 4 + 0] = v.x; ftile[row][ch * 4 + 1] = v.y;
        ftile[row][ch * 4 + 2] = v.z; ftile[row][ch * 4 + 3] = v.w;
    }
    __syncthreads();
#pragma unroll
    for (int it = 0; it < 16; ++it) {
        int w = tid + it * 256;          // 4096 dwords: K row-major
        int row = w >> 6, cp = w & 63;
        unsigned int d = pkh(ftile[row][2 * cp], ftile[row][2 * cp + 1]);
        int byte = row * 256 + cp * 4;
        byte ^= (row & 7) << 4;
        *(unsigned int*)(kf + byte) = d;
    }
#pragma unroll
    for (int it = 0; it < 16; ++it) {
        int w = tid + it * 256;          // 4096 dwords: V transposed
        int dd = w >> 5, jp = w & 31;
        unsigned int d = pkh(ftile[2 * jp][dd], ftile[2 * jp + 1][dd]);
        int byte = dd * 128 + jp * 4;
        byte ^= (dd & 7) << 4;
        *(unsigned int*)(vt + byte) = d;
    }
}

// ---------------- main: swapped-QK^T fp16 flash attention ----------------
__global__ __launch_bounds__(256) void bimodal_attn_fp16(
    const float* __restrict__ X, const float* __restrict__ Y,
    const unsigned short* __restrict__ WS, float* __restrict__ Out)
{
    const int orig = blockIdx.x;
    const int wg = (orig & 7) * 64 + (orig >> 3);   // XCD-aware swizzle (512 = 8*64)
    const int qt = wg & 31;
    const int p  = (wg >> 5) & 1;
    const int b  = wg >> 6;

    const float* Q = p ? Y : X;
    const int kvmat = p ? 0 : 1;   // pass0: KV=Y(mat1); pass1: KV=X(mat0)
    const int ocol = p * D;

    __shared__ unsigned short Ksh[KT * D];   // 16 KB, pre-swizzled image
    __shared__ unsigned short Vsh[D * KT];   // 16 KB, pre-swizzled V^T image
    __shared__ unsigned int   Psh[4][16 * 36]; // per-wave P, [q-row][36-dword pitch]

    const int tid = threadIdx.x;
    const int wv = tid >> 6;
    const int lane = tid & 63;
    const int c = lane & 15;
    const int g = lane >> 4;
    const int i0 = qt * QT + wv * 16;

    // Q fragments (B-operand): Q[c][kc*32+8g+i], fp16 RNE
    const float* qrow = Q + ((size_t)(b * S + i0 + c)) * D;
    f16x8 qf[4];
#pragma unroll
    for (int kc = 0; kc < 4; ++kc) {
        const float* qp = qrow + kc * 32 + g * 8;
        float4 f0 = *(const float4*)qp;
        float4 f1 = *(const float4*)(qp + 4);
        f16x8 tq;
        tq[0] = (_Float16)f0.x; tq[1] = (_Float16)f0.y; tq[2] = (_Float16)f0.z; tq[3] = (_Float16)f0.w;
        tq[4] = (_Float16)f1.x; tq[5] = (_Float16)f1.y; tq[6] = (_Float16)f1.z; tq[7] = (_Float16)f1.w;
        qf[kc] = tq;
    }

    f32x4 o[8];
#pragma unroll
    for (int nb = 0; nb < 8; ++nb) o[nb] = (f32x4){0.f, 0.f, 0.f, 0.f};
    float m = -1e30f, l = 0.f;

    const char* kfb = (const char*)(WS + (size_t)(kvmat * 2 + 0) * (8ull * S * D)) + (size_t)b * (S * D * 2);
    const char* vtb = (const char*)(WS + (size_t)(kvmat * 2 + 1) * (8ull * S * D)) + (size_t)b * (S * D * 2);
    const int soff = wv * 4096 + lane * 16;

    for (int tt = 0; tt < S / KT; ++tt) {
        __syncthreads();
        {   // linear staging of pre-swizzled tiles
            const char* kt = kfb + tt * 16384;
            const char* vp = vtb + tt * 16384;
            u32x4 ka[4], va[4];
#pragma unroll
            for (int i = 0; i < 4; ++i) ka[i] = *(const u32x4*)(kt + soff + i * 1024);
#pragma unroll
            for (int i = 0; i < 4; ++i) va[i] = *(const u32x4*)(vp + soff + i * 1024);
#pragma unroll
            for (int i = 0; i < 4; ++i) *(u32x4*)((char*)Ksh + soff + i * 1024) = ka[i];
#pragma unroll
            for (int i = 0; i < 4; ++i) *(u32x4*)((char*)Vsh + soff + i * 1024) = va[i];
        }
        __syncthreads();

        // S^T tile: D[j_local=4g+r][q=c], A = K-frag, B = Q-frag
        f32x4 sT[4];
        __builtin_amdgcn_s_setprio(1);
#pragma unroll
        for (int nb = 0; nb < 4; ++nb) {
            f32x4 acc = (f32x4){0.f, 0.f, 0.f, 0.f};
#pragma unroll
            for (int kc = 0; kc < 4; ++kc) {
                int byte = (nb * 16 + c) * 256 + kc * 64 + g * 16;
                byte ^= (c & 7) << 4;
                f16x8 kA = *(const f16x8*)((const char*)Ksh + byte);
                acc = MFMA16F(kA, qf[kc], acc);
            }
            sT[nb] = acc;
        }
        __builtin_amdgcn_s_setprio(0);

        // lane-local online softmax (this lane's q-row is c)
        float pmax = fmaxf(fmaxf(sT[0][0], sT[0][1]), fmaxf(sT[0][2], sT[0][3]));
#pragma unroll
        for (int nb = 1; nb < 4; ++nb)
            pmax = fmaxf(pmax, fmaxf(fmaxf(sT[nb][0], sT[nb][1]), fmaxf(sT[nb][2], sT[nb][3])));
        pmax = fmaxf(pmax, __shfl_xor(pmax, 16));
        pmax = fmaxf(pmax, __shfl_xor(pmax, 32));
        if (!__all(pmax - m <= 8.f)) {       // T13 defer-max, THR=8
            float mn = fmaxf(m, pmax);
            float alpha = __expf(m - mn);
            m = mn; l *= alpha;
#pragma unroll
            for (int nb = 0; nb < 8; ++nb) {
                o[nb][0] *= alpha; o[nb][1] *= alpha;
                o[nb][2] *= alpha; o[nb][3] *= alpha;
            }
        }
        float rs = 0.f;
        unsigned int* pr = Psh[wv] + c * 36;
#pragma unroll
        for (int nb = 0; nb < 4; ++nb) {
            float e0 = __expf(sT[nb][0] - m), e1 = __expf(sT[nb][1] - m);
            float e2 = __expf(sT[nb][2] - m), e3 = __expf(sT[nb][3] - m);
            rs += (e0 + e1) + (e2 + e3);
            pr[nb * 8 + 2 * g + 0] = pkh(e0, e1);   // j-pair (nb*16+4g)/2
            pr[nb * 8 + 2 * g + 1] = pkh(e2, e3);
        }
        rs += __shfl_xor(rs, 16);
        rs += __shfl_xor(rs, 32);
        l += rs;

        __builtin_amdgcn_wave_barrier();     // order Psh writes before cross-lane reads

        union { f16x8 v; u32x4 u; } pf0, pf1;
        pf0.u = *(const u32x4*)(Psh[wv] + c * 36 + 0 * 16 + 4 * g);
        pf1.u = *(const u32x4*)(Psh[wv] + c * 36 + 1 * 16 + 4 * g);

        // O^T += V^T-frag (A) * P^T-frag (B): lane accumulates O[q=c][d=nb*16+4g+r]
        __builtin_amdgcn_s_setprio(1);
#pragma unroll
        for (int nb = 0; nb < 8; ++nb) {
            int byte0 = (nb * 16 + c) * 128 + 0 * 64 + g * 16; byte0 ^= (c & 7) << 4;
            int byte1 = (nb * 16 + c) * 128 + 1 * 64 + g * 16; byte1 ^= (c & 7) << 4;
            f16x8 v0 = *(const f16x8*)((const char*)Vsh + byte0);
            f16x8 v1 = *(const f16x8*)((const char*)Vsh + byte1);
            o[nb] = MFMA16F(v0, pf0.v, o[nb]);
            o[nb] = MFMA16F(v1, pf1.v, o[nb]);
        }
        __builtin_amdgcn_s_setprio(0);
    }

    // epilogue: normalize, gate, store float4 (all lane-local)
    const float inv = 1.f / l;
    float* outr = Out + ((size_t)(b * S + i0 + c)) * (2 * D) + ocol;
#pragma unroll
    for (int nb = 0; nb < 8; ++nb) {
        int d0 = nb * 16 + 4 * g;
        float4 qv = *(const float4*)(qrow + d0);
        float4 ov;
        ov.x = o[nb][0] * inv * qv.x;
        ov.y = o[nb][1] * inv * qv.y;
        ov.z = o[nb][2] * inv * qv.z;
        ov.w = o[nb][3] * inv * qv.w;
        *(float4*)(outr + d0) = ov;
    }
}

// ---------------- fallback (round-2 verified kernel) ----------------
__global__ __launch_bounds__(256) void bimodal_attn_fb(
    const float* __restrict__ X, const float* __restrict__ Y,
    float* __restrict__ Out)
{
    const int bid = blockIdx.x;
    const int qt = bid & 31;
    const int p  = (bid >> 5) & 1;
    const int b  = bid >> 6;

    const float* Q  = p ? Y : X;
    const float* KV = p ? X : Y;
    const int ocol = p * D;

    __shared__ unsigned short Khi[KT * D];
    __shared__ unsigned short Klo[KT * D];
    __shared__ unsigned short Vt[D * KT];
    __shared__ unsigned short Psh[4][16 * 72];

    const int tid = threadIdx.x;
    const int wv = tid >> 6;
    const int lane = tid & 63;
    const int c = lane & 15;
    const int g = lane >> 4;
    const int i0 = qt * QT + wv * 16;

    const float* qbase = Q + ((size_t)(b * S + i0 + c)) * D;
    bf16x8 qhi[4], qlo[4];
#pragma unroll
    for (int kc = 0; kc < 4; ++kc) {
        const float* qp = qbase + kc * 32 + g * 8;
        float4 f0 = *(const float4*)qp;
        float4 f1 = *(const float4*)(qp + 4);
        float fv[8] = {f0.x, f0.y, f0.z, f0.w, f1.x, f1.y, f1.z, f1.w};
        bf16x8 th, tl;
#pragma unroll
        for (int i = 0; i < 8; ++i) {
            unsigned short h = f2b(fv[i]);
            th[i] = (short)h;
            tl[i] = (short)f2b(fv[i] - b2f(h));
        }
        qhi[kc] = th; qlo[kc] = tl;
    }

    f32x4 o[8];
#pragma unroll
    for (int nb = 0; nb < 8; ++nb) { o[nb][0] = 0.f; o[nb][1] = 0.f; o[nb][2] = 0.f; o[nb][3] = 0.f; }
    float m[4], l[4];
#pragma unroll
    for (int r = 0; r < 4; ++r) { m[r] = -1e30f; l[r] = 0.f; }

    const float* kvb = KV + (size_t)b * S * D;
    unsigned short* pbuf = Psh[wv];

    for (int j0 = 0; j0 < S; j0 += KT) {
#pragma unroll
        for (int t = 0; t < 4; ++t) {
            int task = tid + t * 256;
            int jr = task >> 4, sl = task & 15;
            const float* src = kvb + (size_t)(j0 + jr) * D + sl * 8;
            float4 f0 = *(const float4*)src;
            float4 f1 = *(const float4*)(src + 4);
            float fv[8] = {f0.x, f0.y, f0.z, f0.w, f1.x, f1.y, f1.z, f1.w};
            unsigned short hv[8];
            float lv[8];
#pragma unroll
            for (int i = 0; i < 8; ++i) {
                hv[i] = f2b(fv[i]);
                lv[i] = fv[i] - b2f(hv[i]);
            }
            uint4 wh, wl;
            wh.x = (unsigned int)hv[0] | ((unsigned int)hv[1] << 16);
            wh.y = (unsigned int)hv[2] | ((unsigned int)hv[3] << 16);
            wh.z = (unsigned int)hv[4] | ((unsigned int)hv[5] << 16);
            wh.w = (unsigned int)hv[6] | ((unsigned int)hv[7] << 16);
            wl.x = pack2(lv[0], lv[1]); wl.y = pack2(lv[2], lv[3]);
            wl.z = pack2(lv[4], lv[5]); wl.w = pack2(lv[6], lv[7]);
            int byte = jr * 256 + sl * 16;
            byte ^= (jr & 7) << 4;
            *(uint4*)((char*)Khi + byte) = wh;
            *(uint4*)((char*)Klo + byte) = wl;
        }
#pragma unroll
        for (int t = 0; t < 2; ++t) {
            int task = tid + t * 256;
            int jp = task & 31, dc = task >> 5;
            const float* s0 = kvb + (size_t)(j0 + 2 * jp) * D + dc * 8;
            const float* s1 = s0 + D;
            float4 a0 = *(const float4*)s0, a1 = *(const float4*)(s0 + 4);
            float4 b0 = *(const float4*)s1, b1 = *(const float4*)(s1 + 4);
            float av[8] = {a0.x, a0.y, a0.z, a0.w, a1.x, a1.y, a1.z, a1.w};
            float bv[8] = {b0.x, b0.y, b0.z, b0.w, b1.x, b1.y, b1.z, b1.w};
#pragma unroll
            for (int i = 0; i < 8; ++i) {
                int d = dc * 8 + i;
                int byte = d * 128 + jp * 4;
                byte ^= (d & 7) << 4;
                *(unsigned int*)((char*)Vt + byte) = pack2(av[i], bv[i]);
            }
        }
        __syncthreads();

        f32x4 sF[4];
#pragma unroll
        for (int nb = 0; nb < 4; ++nb) {
            f32x4 acc; acc[0] = 0.f; acc[1] = 0.f; acc[2] = 0.f; acc[3] = 0.f;
#pragma unroll
            for (int kc = 0; kc < 4; ++kc) {
                int row = nb * 16 + c;
                int byte = row * 256 + (kc * 32 + g * 8) * 2;
                byte ^= (row & 7) << 4;
                bf16x8 kh = *(const bf16x8*)((char*)Khi + byte);
                bf16x8 kl = *(const bf16x8*)((char*)Klo + byte);
                acc = MFMA16B(qhi[kc], kh, acc);
                acc = MFMA16B(qhi[kc], kl, acc);
                acc = MFMA16B(qlo[kc], kh, acc);
            }
            sF[nb] = acc;
        }

#pragma unroll
        for (int r = 0; r < 4; ++r) {
            float v = fmaxf(fmaxf(sF[0][r], sF[1][r]), fmaxf(sF[2][r], sF[3][r]));
            v = fmaxf(v, __shfl_xor(v, 1));
            v = fmaxf(v, __shfl_xor(v, 2));
            v = fmaxf(v, __shfl_xor(v, 4));
            v = fmaxf(v, __shfl_xor(v, 8));
            float mn = fmaxf(m[r], v);
            float alpha = __expf(m[r] - mn);
            m[r] = mn;
            float rs = 0.f;
#pragma unroll
            for (int nb = 0; nb < 4; ++nb) {
                float pv = __expf(sF[nb][r] - mn);
                sF[nb][r] = pv;
                rs += pv;
            }
            rs += __shfl_xor(rs, 1);
            rs += __shfl_xor(rs, 2);
            rs += __shfl_xor(rs, 4);
            rs += __shfl_xor(rs, 8);
            l[r] = l[r] * alpha + rs;
#pragma unroll
            for (int nb = 0; nb < 8; ++nb) o[nb][r] *= alpha;
        }

#pragma unroll
        for (int nb = 0; nb < 4; ++nb)
#pragma unroll
            for (int r = 0; r < 4; ++r)
                pbuf[(g * 4 + r) * 72 + nb * 16 + c] = f2b(sF[nb][r]);

        bf16x8 pa[2];
#pragma unroll
        for (int kc = 0; kc < 2; ++kc)
            pa[kc] = *(const bf16x8*)(pbuf + c * 72 + kc * 32 + g * 8);

#pragma unroll
        for (int nb = 0; nb < 8; ++nb) {
#pragma unroll
            for (int kc = 0; kc < 2; ++kc) {
                int d = nb * 16 + c;
                int byte = d * 128 + (kc * 32 + g * 8) * 2;
                byte ^= (d & 7) << 4;
                bf16x8 vf = *(const bf16x8*)((char*)Vt + byte);
                o[nb] = MFMA16B(pa[kc], vf, o[nb]);
            }
        }
        __syncthreads();
    }

    float* outb = Out + ((size_t)(b * S + i0)) * (2 * D) + ocol;
    const float* qg = Q + (size_t)(b * S + i0) * D;
#pragma unroll
    for (int r = 0; r < 4; ++r) {
        int row = g * 4 + r;
        float inv = 1.f / l[r];
#pragma unroll
        for (int nb = 0; nb < 8; ++nb) {
            int col = nb * 16 + c;
            float qv = qg[(size_t)row * D + col];
            outb[(size_t)row * (2 * D) + col] = o[nb][r] * inv * qv;
        }
    }
}

extern "C" void kernel_launch(void* const* d_in, const int* in_sizes, int n_in,
                              void* d_out, int out_size, void* d_ws, size_t ws_size,
                              hipStream_t stream) {
    const float* x = (const float*)d_in[0];
    const float* y = (const float*)d_in[1];
    float* out = (float*)d_out;
    const int B = 8;
    dim3 grid(B * 2 * (S / QT));
    dim3 block(256);
    const size_t need = 4ull * 8 * S * D * 2;   // 16 MB fp16 staging
    if (ws_size >= need) {
        hipLaunchKernelGGL(bimodal_prep, grid, block, 0, stream, x, y, (unsigned short*)d_ws);
        hipLaunchKernelGGL(bimodal_attn_fp16, grid, block, 0, stream, x, y,
                           (const unsigned short*)d_ws, out);
    } else {
        hipLaunchKernelGGL(bimodal_attn_fb, grid, block, 0, stream, x, y, out);
    }
}